// Round 1
// baseline (544.103 us; speedup 1.0000x reference)
//
#include <hip/hip_runtime.h>
#include <math.h>

#define VOCAB 30000
#define DMODEL 256
#define NHEAD 4
#define DKK 64
#define SEQ 1024
#define BATCH 16
#define HID 256
#define MROWS (BATCH*SEQ)   // 16384
#define NEGINF (-1e10f)
#define SCALE 0.125f        // 1/sqrt(64)

// ---------------- transpose (R x C) -> (C x R) ----------------
__global__ void transpose_k(const float* __restrict__ in, float* __restrict__ out, int R, int C) {
    __shared__ float t[32][33];
    int c0 = blockIdx.x * 32, r0 = blockIdx.y * 32;
    int tx = threadIdx.x, ty = threadIdx.y; // 32 x 8
    for (int i = 0; i < 32; i += 8) {
        int r = r0 + ty + i, c = c0 + tx;
        if (r < R && c < C) t[ty + i][tx] = in[(size_t)r * C + c];
    }
    __syncthreads();
    for (int i = 0; i < 32; i += 8) {
        int c = c0 + ty + i, r = r0 + tx;
        if (c < C && r < R) out[(size_t)c * R + r] = t[tx][ty + i];
    }
}

// ---------------- positional encoding table (f64 math) ----------------
__global__ void pe_kernel(float* __restrict__ pe) {
    int idx = blockIdx.x * 256 + threadIdx.x; // SEQ*128
    if (idx >= SEQ * 128) return;
    int n = idx >> 7, d2 = idx & 127;
    double down = exp((double)(2 * d2) * (-9.210340371976184 / 256.0)); // -ln(10000)/D
    double ang = (double)n * down;
    pe[n * DMODEL + 2 * d2]     = (float)(sin(ang) * 0.1);
    pe[n * DMODEL + 2 * d2 + 1] = (float)(cos(ang) * 0.1);
}

// ---------------- per-batch span from attention_mask ----------------
__global__ void span_kernel(const int* __restrict__ mask, int* __restrict__ spans) {
    int b = blockIdx.x;
    __shared__ int smin, smax;
    if (threadIdx.x == 0) { smin = SEQ; smax = -1; }
    __syncthreads();
    int lmin = SEQ, lmax = -1;
    for (int i = threadIdx.x; i < SEQ; i += 256) {
        if (mask[b * SEQ + i] != 0) { lmin = min(lmin, i); lmax = max(lmax, i); }
    }
    atomicMin(&smin, lmin);
    atomicMax(&smax, lmax);
    __syncthreads();
    if (threadIdx.x == 0) {
        int st, en;
        if (smax < 0) { st = 0; en = SEQ - 1; }   // argmax-of-zeros semantics
        else          { st = smin; en = smax; }   // en = last-true index (exclusive in span test)
        spans[b * 2] = st; spans[b * 2 + 1] = en;
    }
}

// ---------------- embedding gather + pos enc ----------------
__global__ void embed_kernel(const int* __restrict__ ids, const float* __restrict__ embT,
                             const float* __restrict__ emb_b, const float* __restrict__ pe,
                             float* __restrict__ x0) {
    int bn = blockIdx.x;
    int d = threadIdx.x;
    int id = ids[bn];
    int n = bn & (SEQ - 1);
    x0[(size_t)bn * DMODEL + d] = embT[(size_t)id * DMODEL + d] + emb_b[d] + pe[n * DMODEL + d];
}

// ---------------- GEMM: C = A(M x 256) @ WT(256 x 256)  (+bias, epilogue) ----------------
// MODE 0: plain+bias   MODE 1: qkv scatter to (B,H,N,DK)   MODE 2: +bias+residual   MODE 3: +bias+gelu
template <int MODE>
__global__ __launch_bounds__(256) void gemm256(const float* __restrict__ A,
                                               const float* __restrict__ WT,
                                               const float* __restrict__ bias,
                                               const float* __restrict__ Rres,
                                               float* __restrict__ C) {
    __shared__ float As[32][68];   // [k][r], padded
    __shared__ float Ws[32][128];  // [k][c]
    int tid = threadIdx.x;
    int c0 = blockIdx.x * 128;
    int m0 = blockIdx.y * 64;
    int tx = tid & 31, ty = tid >> 5;
    float acc[8][4] = {};

    for (int k0 = 0; k0 < 256; k0 += 32) {
        #pragma unroll
        for (int i = 0; i < 2; i++) {
            int f4 = tid + 256 * i;
            int r = f4 >> 3, k4 = f4 & 7;
            float4 av = *(const float4*)(A + (size_t)(m0 + r) * 256 + k0 + 4 * k4);
            As[4 * k4 + 0][r] = av.x; As[4 * k4 + 1][r] = av.y;
            As[4 * k4 + 2][r] = av.z; As[4 * k4 + 3][r] = av.w;
        }
        #pragma unroll
        for (int i = 0; i < 4; i++) {
            int f4 = tid + 256 * i;
            int kk = f4 >> 5, c4 = f4 & 31;
            *(float4*)(&Ws[kk][4 * c4]) = *(const float4*)(WT + (size_t)(k0 + kk) * 256 + c0 + 4 * c4);
        }
        __syncthreads();
        #pragma unroll 8
        for (int k = 0; k < 32; k++) {
            float a[8], bb[4];
            *(float4*)(a)     = *(const float4*)(&As[k][ty * 8]);
            *(float4*)(a + 4) = *(const float4*)(&As[k][ty * 8 + 4]);
            *(float4*)(bb)    = *(const float4*)(&Ws[k][tx * 4]);
            #pragma unroll
            for (int i = 0; i < 8; i++)
                #pragma unroll
                for (int j = 0; j < 4; j++)
                    acc[i][j] = fmaf(a[i], bb[j], acc[i][j]);
        }
        __syncthreads();
    }

    float bv[4];
    *(float4*)bv = *(const float4*)(bias + c0 + tx * 4);
    #pragma unroll
    for (int i = 0; i < 8; i++) {
        int m = m0 + ty * 8 + i;
        float4 o;
        o.x = acc[i][0] + bv[0]; o.y = acc[i][1] + bv[1];
        o.z = acc[i][2] + bv[2]; o.w = acc[i][3] + bv[3];
        if (MODE == 2) {
            float4 rv = *(const float4*)(Rres + (size_t)m * 256 + c0 + tx * 4);
            o.x += rv.x; o.y += rv.y; o.z += rv.z; o.w += rv.w;
        }
        if (MODE == 3) {
            o.x = 0.5f * o.x * (1.f + erff(o.x * 0.70710678118654752f));
            o.y = 0.5f * o.y * (1.f + erff(o.y * 0.70710678118654752f));
            o.z = 0.5f * o.z * (1.f + erff(o.z * 0.70710678118654752f));
            o.w = 0.5f * o.w * (1.f + erff(o.w * 0.70710678118654752f));
        }
        if (MODE == 1) {
            int e0 = c0 + tx * 4;
            int hh = e0 >> 6, dk = e0 & 63;
            int b = m >> 10, n = m & 1023;
            *(float4*)(C + (((size_t)b * NHEAD + hh) * SEQ + n) * DKK + dk) = o;
        } else {
            *(float4*)(C + (size_t)m * 256 + c0 + tx * 4) = o;
        }
    }
}

// ---------------- flash-style fp32 attention ----------------
__global__ __launch_bounds__(256) void attn_kernel(const float* __restrict__ q,
                                                   const float* __restrict__ k,
                                                   const float* __restrict__ v,
                                                   const int* __restrict__ spans,
                                                   float* __restrict__ attb) {
    int b = blockIdx.z, h = blockIdx.y, rt = blockIdx.x;
    const size_t base = ((size_t)(b * NHEAD + h)) * SEQ * DKK;
    __shared__ float QsT[64][68];  // [dk][r]
    __shared__ float KVs[64][68];  // K: [dk][c]; then V: [c][dk]
    __shared__ float Ps[64][68];   // [r][c]
    int tid = threadIdx.x;
    int tx = tid & 15, ty = tid >> 4;
    int start = spans[b * 2], end = spans[b * 2 + 1];

    #pragma unroll
    for (int i = 0; i < 4; i++) {
        int f4 = tid + 256 * i;
        int r = f4 >> 4, k4 = f4 & 15;
        float4 qv = *(const float4*)(q + base + (size_t)(rt * 64 + r) * DKK + 4 * k4);
        QsT[4 * k4 + 0][r] = qv.x; QsT[4 * k4 + 1][r] = qv.y;
        QsT[4 * k4 + 2][r] = qv.z; QsT[4 * k4 + 3][r] = qv.w;
    }

    float o[4][4] = {};
    float mrow[4], lrow[4];
    bool rowok[4];
    #pragma unroll
    for (int i = 0; i < 4; i++) {
        mrow[i] = -INFINITY; lrow[i] = 0.f;
        int n = rt * 64 + ty * 4 + i;
        rowok[i] = (n >= start) && (n < end);
    }

    for (int ct = 0; ct < 16; ct++) {
        __syncthreads();  // prev PV reads done before K overwrite
        #pragma unroll
        for (int i = 0; i < 4; i++) {
            int f4 = tid + 256 * i;
            int cc = f4 >> 4, k4 = f4 & 15;
            float4 kv = *(const float4*)(k + base + (size_t)(ct * 64 + cc) * DKK + 4 * k4);
            KVs[4 * k4 + 0][cc] = kv.x; KVs[4 * k4 + 1][cc] = kv.y;
            KVs[4 * k4 + 2][cc] = kv.z; KVs[4 * k4 + 3][cc] = kv.w;
        }
        __syncthreads();

        float s[4][4] = {};
        #pragma unroll 8
        for (int kk = 0; kk < 64; kk++) {
            float a[4], bb[4];
            *(float4*)a  = *(const float4*)(&QsT[kk][ty * 4]);
            *(float4*)bb = *(const float4*)(&KVs[kk][tx * 4]);
            #pragma unroll
            for (int i = 0; i < 4; i++)
                #pragma unroll
                for (int j = 0; j < 4; j++)
                    s[i][j] = fmaf(a[i], bb[j], s[i][j]);
        }

        int cbase = ct * 64 + tx * 4;
        bool colok[4];
        #pragma unroll
        for (int j = 0; j < 4; j++) colok[j] = (cbase + j >= start) && (cbase + j < end);
        #pragma unroll
        for (int i = 0; i < 4; i++)
            #pragma unroll
            for (int j = 0; j < 4; j++) {
                float sv = s[i][j] * SCALE;
                if (!(rowok[i] && colok[j])) sv += NEGINF;  // exact jax-fp32 mask semantics
                s[i][j] = sv;
            }

        float mt[4];
        #pragma unroll
        for (int i = 0; i < 4; i++)
            mt[i] = fmaxf(fmaxf(s[i][0], s[i][1]), fmaxf(s[i][2], s[i][3]));
        #pragma unroll
        for (int off = 1; off < 16; off <<= 1)
            #pragma unroll
            for (int i = 0; i < 4; i++) mt[i] = fmaxf(mt[i], __shfl_xor(mt[i], off));

        float p[4][4], rs[4], alpha[4];
        #pragma unroll
        for (int i = 0; i < 4; i++) {
            float mnew = fmaxf(mrow[i], mt[i]);
            alpha[i] = expf(mrow[i] - mnew);
            mrow[i] = mnew;
            rs[i] = 0.f;
            #pragma unroll
            for (int j = 0; j < 4; j++) { p[i][j] = expf(s[i][j] - mnew); rs[i] += p[i][j]; }
        }
        #pragma unroll
        for (int off = 1; off < 16; off <<= 1)
            #pragma unroll
            for (int i = 0; i < 4; i++) rs[i] += __shfl_xor(rs[i], off);
        #pragma unroll
        for (int i = 0; i < 4; i++) {
            lrow[i] = lrow[i] * alpha[i] + rs[i];
            #pragma unroll
            for (int j = 0; j < 4; j++) o[i][j] *= alpha[i];
        }

        __syncthreads();  // S-phase reads of KVs done
        #pragma unroll
        for (int i = 0; i < 4; i++)
            *(float4*)(&Ps[ty * 4 + i][tx * 4]) = *(float4*)(p[i]);
        #pragma unroll
        for (int i = 0; i < 4; i++) {
            int f4 = tid + 256 * i;
            int cc = f4 >> 4, k4 = f4 & 15;
            *(float4*)(&KVs[cc][4 * k4]) = *(const float4*)(v + base + (size_t)(ct * 64 + cc) * DKK + 4 * k4);
        }
        __syncthreads();

        #pragma unroll 2
        for (int c4 = 0; c4 < 16; c4++) {
            float a4[4][4], b4[4][4];
            #pragma unroll
            for (int i = 0; i < 4; i++)
                *(float4*)(a4[i]) = *(const float4*)(&Ps[ty * 4 + i][c4 * 4]);
            #pragma unroll
            for (int cc = 0; cc < 4; cc++)
                *(float4*)(b4[cc]) = *(const float4*)(&KVs[4 * c4 + cc][tx * 4]);
            #pragma unroll
            for (int cc = 0; cc < 4; cc++)
                #pragma unroll
                for (int i = 0; i < 4; i++)
                    #pragma unroll
                    for (int j = 0; j < 4; j++)
                        o[i][j] = fmaf(a4[i][cc], b4[cc][j], o[i][j]);
        }
    }

    #pragma unroll
    for (int i = 0; i < 4; i++) {
        float inv = 1.f / lrow[i];
        float4 ov;
        ov.x = o[i][0] * inv; ov.y = o[i][1] * inv;
        ov.z = o[i][2] * inv; ov.w = o[i][3] * inv;
        *(float4*)(attb + ((size_t)b * SEQ + rt * 64 + ty * 4 + i) * DMODEL + h * DKK + tx * 4) = ov;
    }
}

// ---------------- mean pool (two stage) ----------------
__global__ void pool_partial(const float* __restrict__ x2, float* __restrict__ part) {
    int ch = blockIdx.x, b = blockIdx.y, d = threadIdx.x;
    float s = 0.f;
    for (int n = ch * 32; n < ch * 32 + 32; n++)
        s += x2[((size_t)b * SEQ + n) * DMODEL + d];
    part[((size_t)b * 32 + ch) * DMODEL + d] = s;
}
__global__ void pool_final(const float* __restrict__ part, float* __restrict__ pooled) {
    int b = blockIdx.x, d = threadIdx.x;
    float s = 0.f;
    for (int ch = 0; ch < 32; ch++) s += part[((size_t)b * 32 + ch) * DMODEL + d];
    pooled[b * DMODEL + d] = s * (1.f / 1024.f);
}

// ---------------- MLP head with eval BatchNorm ----------------
__global__ __launch_bounds__(128) void head_kernel(const float* __restrict__ pooled,
                                                   const float* __restrict__ h1_w, const float* __restrict__ h1_b,
                                                   const float* __restrict__ g, const float* __restrict__ be,
                                                   const float* __restrict__ mu, const float* __restrict__ var,
                                                   const float* __restrict__ h2_w, const float* __restrict__ h2_b,
                                                   float* __restrict__ out) {
    int b = blockIdx.x, j = threadIdx.x;
    __shared__ float pl[256];
    __shared__ float red[128];
    pl[j] = pooled[b * DMODEL + j];
    pl[j + 128] = pooled[b * DMODEL + j + 128];
    __syncthreads();
    float s = 0.f;
    for (int d = 0; d < 256; d++) s = fmaf(pl[d], h1_w[j * 256 + d], s);
    s += h1_b[j];
    s = (s - mu[j]) / sqrtf(var[j] + 1e-5f) * g[j] + be[j];
    s = fmaxf(s, 0.f);
    red[j] = s * h2_w[j];
    __syncthreads();
    for (int off = 64; off; off >>= 1) {
        if (j < off) red[j] += red[j + off];
        __syncthreads();
    }
    if (j == 0) out[b] = red[0] + h2_b[0];
}

// ---------------- launch ----------------
extern "C" void kernel_launch(void* const* d_in, const int* in_sizes, int n_in,
                              void* d_out, int out_size, void* d_ws, size_t ws_size,
                              hipStream_t stream) {
    (void)in_sizes; (void)n_in; (void)out_size; (void)ws_size;
    const int*   ids    = (const int*)d_in[0];
    const int*   amask  = (const int*)d_in[1];
    const float* emb_W  = (const float*)d_in[2];
    const float* emb_b  = (const float*)d_in[3];
    const float* wq = (const float*)d_in[4],  *bq = (const float*)d_in[5];
    const float* wk = (const float*)d_in[6],  *bk = (const float*)d_in[7];
    const float* wv = (const float*)d_in[8],  *bv = (const float*)d_in[9];
    const float* fcw = (const float*)d_in[10], *fcb = (const float*)d_in[11];
    const float* f1w = (const float*)d_in[12], *f1b = (const float*)d_in[13];
    const float* f2w = (const float*)d_in[14], *f2b = (const float*)d_in[15];
    const float* h1w = (const float*)d_in[16], *h1b = (const float*)d_in[17];
    const float* bng = (const float*)d_in[18], *bnb = (const float*)d_in[19];
    const float* bnm = (const float*)d_in[20], *bnv = (const float*)d_in[21];
    const float* h2w = (const float*)d_in[22], *h2b = (const float*)d_in[23];
    float* out = (float*)d_out;
    float* ws = (float*)d_ws;

    const size_t O_EMBT = 0;                            // 7,680,000 (reused as attb later)
    const size_t O_WT   = O_EMBT + (size_t)VOCAB * DMODEL;
    const size_t O_PE   = O_WT + 6 * 65536;
    const size_t O_X0   = O_PE + SEQ * DMODEL;
    const size_t O_Q    = O_X0 + (size_t)MROWS * DMODEL;   // later x1
    const size_t O_K    = O_Q  + (size_t)MROWS * DMODEL;   // later hbuf
    const size_t O_V    = O_K  + (size_t)MROWS * DMODEL;   // later x2
    const size_t O_PART = O_V  + (size_t)MROWS * DMODEL;
    const size_t O_POOL = O_PART + BATCH * 32 * DMODEL;
    const size_t O_SPAN = O_POOL + BATCH * DMODEL;

    float* embT = ws + O_EMBT;
    float* WT   = ws + O_WT;
    float* pe   = ws + O_PE;
    float* x0   = ws + O_X0;
    float* qb   = ws + O_Q;
    float* kb   = ws + O_K;
    float* vb   = ws + O_V;
    float* attb = ws + O_EMBT;  // reuse: embT dead after embed
    float* x1   = ws + O_Q;     // reuse: q dead after attention
    float* hbuf = ws + O_K;
    float* x2   = ws + O_V;
    float* part = ws + O_PART;
    float* pooled = ws + O_POOL;
    int* spans  = (int*)(ws + O_SPAN);

    dim3 tb(32, 8);
    transpose_k<<<dim3((VOCAB + 31) / 32, 8), tb, 0, stream>>>(emb_W, embT, DMODEL, VOCAB);
    transpose_k<<<dim3(8, 8), tb, 0, stream>>>(wq,  WT + 0 * 65536, 256, 256);
    transpose_k<<<dim3(8, 8), tb, 0, stream>>>(wk,  WT + 1 * 65536, 256, 256);
    transpose_k<<<dim3(8, 8), tb, 0, stream>>>(wv,  WT + 2 * 65536, 256, 256);
    transpose_k<<<dim3(8, 8), tb, 0, stream>>>(fcw, WT + 3 * 65536, 256, 256);
    transpose_k<<<dim3(8, 8), tb, 0, stream>>>(f1w, WT + 4 * 65536, 256, 256);
    transpose_k<<<dim3(8, 8), tb, 0, stream>>>(f2w, WT + 5 * 65536, 256, 256);
    pe_kernel<<<512, 256, 0, stream>>>(pe);
    span_kernel<<<BATCH, 256, 0, stream>>>(amask, spans);
    embed_kernel<<<MROWS, 256, 0, stream>>>(ids, embT, emb_b, pe, x0);

    dim3 gg(2, MROWS / 64);
    gemm256<1><<<gg, 256, 0, stream>>>(x0, WT + 0 * 65536, bq, nullptr, qb);
    gemm256<1><<<gg, 256, 0, stream>>>(x0, WT + 1 * 65536, bk, nullptr, kb);
    gemm256<1><<<gg, 256, 0, stream>>>(x0, WT + 2 * 65536, bv, nullptr, vb);

    attn_kernel<<<dim3(SEQ / 64, NHEAD, BATCH), 256, 0, stream>>>(qb, kb, vb, spans, attb);

    gemm256<2><<<gg, 256, 0, stream>>>(attb, WT + 3 * 65536, fcb, x0, x1);
    gemm256<3><<<gg, 256, 0, stream>>>(x1,   WT + 4 * 65536, f1b, nullptr, hbuf);
    gemm256<0><<<gg, 256, 0, stream>>>(hbuf, WT + 5 * 65536, f2b, nullptr, x2);

    pool_partial<<<dim3(32, BATCH), 256, 0, stream>>>(x2, part);
    pool_final<<<BATCH, 256, 0, stream>>>(part, pooled);
    head_kernel<<<BATCH, 128, 0, stream>>>(pooled, h1w, h1b, bng, bnb, bnm, bnv, h2w, h2b, out);
}

// Round 2
// 197.467 us; speedup vs baseline: 2.7554x; 2.7554x over previous
//
#include <hip/hip_runtime.h>
#include <math.h>

#define VOCAB 30000
#define DMODEL 256
#define NHEAD 4
#define SEQ 1024
#define BATCH 16
#define MROWS (BATCH*SEQ)   // 16384
#define NEGINF (-1e10f)
#define SCALE 0.125f        // 1/sqrt(64)

typedef __attribute__((ext_vector_type(8))) short bf16x8;
typedef __attribute__((ext_vector_type(4))) float f32x4;

__device__ __forceinline__ unsigned short f2b(float f) {
    unsigned int u = __float_as_uint(f);
    unsigned int r = (u + 0x7FFFu + ((u >> 16) & 1u)) >> 16;
    return (unsigned short)r;
}

// ---------------- transpose (R x C) -> (C x R), fp32 (embedding table only) ----------------
__global__ void transpose_k(const float* __restrict__ in, float* __restrict__ out, int R, int C) {
    __shared__ float t[32][33];
    int c0 = blockIdx.x * 32, r0 = blockIdx.y * 32;
    int tx = threadIdx.x, ty = threadIdx.y; // 32 x 8
    for (int i = 0; i < 32; i += 8) {
        int r = r0 + ty + i, c = c0 + tx;
        if (r < R && c < C) t[ty + i][tx] = in[(size_t)r * C + c];
    }
    __syncthreads();
    for (int i = 0; i < 32; i += 8) {
        int c = c0 + ty + i, r = r0 + tx;
        if (c < C && r < R) out[(size_t)c * R + r] = t[tx][ty + i];
    }
}

// ---------------- positional encoding table (f64 math) ----------------
__global__ void pe_kernel(float* __restrict__ pe) {
    int idx = blockIdx.x * 256 + threadIdx.x; // SEQ*128
    if (idx >= SEQ * 128) return;
    int n = idx >> 7, d2 = idx & 127;
    double down = exp((double)(2 * d2) * (-9.210340371976184 / 256.0));
    double ang = (double)n * down;
    pe[n * DMODEL + 2 * d2]     = (float)(sin(ang) * 0.1);
    pe[n * DMODEL + 2 * d2 + 1] = (float)(cos(ang) * 0.1);
}

// ---------------- per-batch span from attention_mask ----------------
__global__ void span_kernel(const int* __restrict__ mask, int* __restrict__ spans) {
    int b = blockIdx.x;
    __shared__ int smin, smax;
    if (threadIdx.x == 0) { smin = SEQ; smax = -1; }
    __syncthreads();
    int lmin = SEQ, lmax = -1;
    for (int i = threadIdx.x; i < SEQ; i += 256) {
        if (mask[b * SEQ + i] != 0) { lmin = min(lmin, i); lmax = max(lmax, i); }
    }
    atomicMin(&smin, lmin);
    atomicMax(&smax, lmax);
    __syncthreads();
    if (threadIdx.x == 0) {
        int st, en;
        if (smax < 0) { st = 0; en = SEQ - 1; }
        else          { st = smin; en = smax; }
        spans[b * 2] = st; spans[b * 2 + 1] = en;
    }
}

// ---------------- weight fp32 -> bf16 ----------------
__global__ void cvt_w(const float* __restrict__ w, unsigned short* __restrict__ dst) {
    int i = blockIdx.x * 256 + threadIdx.x;
    dst[i] = f2b(w[i]);
}

// ---------------- embedding gather + pos enc -> x0 (fp32) + x0b (bf16) ----------------
__global__ void embed_kernel(const int* __restrict__ ids, const float* __restrict__ embT,
                             const float* __restrict__ emb_b, const float* __restrict__ pe,
                             float* __restrict__ x0, unsigned short* __restrict__ x0b) {
    int bn = blockIdx.x;
    int d = threadIdx.x;
    int id = ids[bn];
    int n = bn & (SEQ - 1);
    float v = embT[(size_t)id * DMODEL + d] + emb_b[d] + pe[n * DMODEL + d];
    x0[(size_t)bn * DMODEL + d] = v;
    x0b[(size_t)bn * DMODEL + d] = f2b(v);
}

// ---------------- bf16 MFMA GEMM: C = A(16384x256) @ W^T  (W row-major 256x256) ----------------
// MODE 0: fp32 out (+bias)          MODE 1: bf16 scatter to (B,H,N,64)
// MODE 2: bf16 out (+bias+residual) MODE 3: bf16 out (+bias+gelu)
// MODE 4: bf16 scatter transposed to (B,H,64,N)
template <int MODE>
__global__ __launch_bounds__(256) void bgemm(const unsigned short* __restrict__ A,
                                             const unsigned short* __restrict__ W,
                                             const float* __restrict__ bias,
                                             const float* __restrict__ Rres,
                                             void* __restrict__ Cout) {
    __shared__ unsigned short As[128 * 64];
    __shared__ unsigned short Bs[128 * 64];
    int tid = threadIdx.x;
    int n0 = blockIdx.x * 128, m0 = blockIdx.y * 128;
    int w = tid >> 6, l = tid & 63;
    int wr = (w >> 1) * 64, wc = (w & 1) * 64;
    int lg = l >> 4, ll = l & 15;
    f32x4 acc[4][4] = {};

    for (int k0 = 0; k0 < 256; k0 += 64) {
        __syncthreads();
        #pragma unroll
        for (int i = 0; i < 4; i++) {
            int s = tid + i * 256;            // 0..1023
            int row = s >> 3;                 // 0..127
            int kb = (s & 7) * 16;            // byte offset in 128B row chunk
            int swz = kb ^ ((row & 7) << 4);
            float4 av = *(const float4*)((const char*)A + (size_t)(m0 + row) * 512 + k0 * 2 + kb);
            *(float4*)((char*)As + row * 128 + swz) = av;
            float4 bv = *(const float4*)((const char*)W + (size_t)(n0 + row) * 512 + k0 * 2 + kb);
            *(float4*)((char*)Bs + row * 128 + swz) = bv;
        }
        __syncthreads();

        bf16x8 af[4][2], bf[4][2];
        #pragma unroll
        for (int mf = 0; mf < 4; mf++) {
            int row = wr + mf * 16 + ll;
            #pragma unroll
            for (int ks = 0; ks < 2; ks++) {
                int off = ((lg * 16 + ks * 64)) ^ ((row & 7) << 4);
                af[mf][ks] = *(const bf16x8*)((const char*)As + row * 128 + off);
            }
        }
        #pragma unroll
        for (int nf = 0; nf < 4; nf++) {
            int row = wc + nf * 16 + ll;
            #pragma unroll
            for (int ks = 0; ks < 2; ks++) {
                int off = ((lg * 16 + ks * 64)) ^ ((row & 7) << 4);
                bf[nf][ks] = *(const bf16x8*)((const char*)Bs + row * 128 + off);
            }
        }
        #pragma unroll
        for (int ks = 0; ks < 2; ks++)
            #pragma unroll
            for (int mf = 0; mf < 4; mf++)
                #pragma unroll
                for (int nf = 0; nf < 4; nf++)
                    acc[mf][nf] = __builtin_amdgcn_mfma_f32_16x16x32_bf16(af[mf][ks], bf[nf][ks], acc[mf][nf], 0, 0, 0);
    }

    float bcol[4];
    #pragma unroll
    for (int nf = 0; nf < 4; nf++) bcol[nf] = bias[n0 + wc + nf * 16 + ll];

    #pragma unroll
    for (int mf = 0; mf < 4; mf++) {
        #pragma unroll
        for (int r = 0; r < 4; r++) {
            int m = m0 + wr + mf * 16 + lg * 4 + r;
            #pragma unroll
            for (int nf = 0; nf < 4; nf++) {
                int n = n0 + wc + nf * 16 + ll;
                float v = acc[mf][nf][r] + bcol[nf];
                if (MODE == 2) v += Rres[(size_t)m * 256 + n];
                if (MODE == 3) v = 0.5f * v * (1.f + erff(v * 0.70710678118654752f));
                if (MODE == 0) {
                    ((float*)Cout)[(size_t)m * 256 + n] = v;
                } else if (MODE == 1) {
                    int bb = m >> 10, ns = m & 1023, hh = n >> 6, dk = n & 63;
                    ((unsigned short*)Cout)[((((size_t)bb * 4 + hh) * 1024) + ns) * 64 + dk] = f2b(v);
                } else if (MODE == 4) {
                    int bb = m >> 10, ns = m & 1023, hh = n >> 6, dk = n & 63;
                    ((unsigned short*)Cout)[((((size_t)bb * 4 + hh) * 64) + dk) * 1024 + ns] = f2b(v);
                } else {
                    ((unsigned short*)Cout)[(size_t)m * 256 + n] = f2b(v);
                }
            }
        }
    }
}

// ---------------- bf16 MFMA flash attention ----------------
// Q,K: (B,H,N,64) bf16; Vt: (B,H,64,N) bf16; out attb: (B,N,256) bf16
__global__ __launch_bounds__(256) void attn_mfma(const unsigned short* __restrict__ Qb,
                                                 const unsigned short* __restrict__ Kb,
                                                 const unsigned short* __restrict__ Vt,
                                                 const int* __restrict__ spans,
                                                 unsigned short* __restrict__ attb) {
    __shared__ unsigned short Ks[64 * 64];
    __shared__ unsigned short Vs[64 * 64];
    __shared__ __align__(16) unsigned short Ps[4][32 * 72];
    int b = blockIdx.z, h = blockIdx.y;
    int q0 = blockIdx.x * 128;
    int tid = threadIdx.x;
    int w = tid >> 6, l = tid & 63;
    int lg = l >> 4, ll = l & 15;
    const size_t bh = (size_t)(b * 4 + h);
    const char* Kp = (const char*)(Kb + bh * SEQ * 64);
    const char* Vp = (const char*)(Vt + bh * 64 * SEQ);
    const unsigned short* Qp = Qb + bh * SEQ * 64;
    int start = spans[b * 2], end = spans[b * 2 + 1];

    // Q fragments in registers
    bf16x8 qf[2][2];
    #pragma unroll
    for (int mf = 0; mf < 2; mf++)
        #pragma unroll
        for (int ks = 0; ks < 2; ks++)
            qf[mf][ks] = *(const bf16x8*)(Qp + (size_t)(q0 + w * 32 + mf * 16 + ll) * 64 + lg * 8 + ks * 32);

    f32x4 o[2][4] = {};
    float mrow[2][4], lrow[2][4];
    bool rowok[2][4];
    #pragma unroll
    for (int mf = 0; mf < 2; mf++)
        #pragma unroll
        for (int r = 0; r < 4; r++) {
            mrow[mf][r] = -INFINITY; lrow[mf][r] = 0.f;
            int rr = q0 + w * 32 + mf * 16 + lg * 4 + r;
            rowok[mf][r] = (rr >= start) && (rr < end);
        }

    for (int ct = 0; ct < 16; ct++) {
        int kv0 = ct * 64;
        __syncthreads();  // all waves done with Ks/Vs of prev iter
        #pragma unroll
        for (int i = 0; i < 2; i++) {
            int s = tid + i * 256;   // 0..511
            int row = s >> 3;        // 0..63
            int kb = (s & 7) * 16;
            int swz = kb ^ ((row & 7) << 4);
            float4 kv = *(const float4*)(Kp + (size_t)(kv0 + row) * 128 + kb);
            *(float4*)((char*)Ks + row * 128 + swz) = kv;
            float4 vv = *(const float4*)(Vp + (size_t)row * 2048 + kv0 * 2 + kb);
            *(float4*)((char*)Vs + row * 128 + swz) = vv;
        }
        __syncthreads();

        // S = Q @ K^T
        f32x4 s[2][4] = {};
        bf16x8 kf[4][2];
        #pragma unroll
        for (int nf = 0; nf < 4; nf++) {
            int row = nf * 16 + ll;
            #pragma unroll
            for (int ks = 0; ks < 2; ks++) {
                int off = (lg * 16 + ks * 64) ^ ((row & 7) << 4);
                kf[nf][ks] = *(const bf16x8*)((const char*)Ks + row * 128 + off);
            }
        }
        #pragma unroll
        for (int ks = 0; ks < 2; ks++)
            #pragma unroll
            for (int mf = 0; mf < 2; mf++)
                #pragma unroll
                for (int nf = 0; nf < 4; nf++)
                    s[mf][nf] = __builtin_amdgcn_mfma_f32_16x16x32_bf16(qf[mf][ks], kf[nf][ks], s[mf][nf], 0, 0, 0);

        // mask + scale (same fp32 semantics as reference: additive -1e10)
        bool colok[4];
        #pragma unroll
        for (int nf = 0; nf < 4; nf++) {
            int c = kv0 + nf * 16 + ll;
            colok[nf] = (c >= start) && (c < end);
        }
        #pragma unroll
        for (int mf = 0; mf < 2; mf++)
            #pragma unroll
            for (int nf = 0; nf < 4; nf++)
                #pragma unroll
                for (int r = 0; r < 4; r++) {
                    float sv = s[mf][nf][r] * SCALE;
                    if (!(rowok[mf][r] && colok[nf])) sv += NEGINF;
                    s[mf][nf][r] = sv;
                }

        // online softmax: rows owned by 16-lane groups
        float mt[2][4];
        #pragma unroll
        for (int mf = 0; mf < 2; mf++)
            #pragma unroll
            for (int r = 0; r < 4; r++)
                mt[mf][r] = fmaxf(fmaxf(s[mf][0][r], s[mf][1][r]), fmaxf(s[mf][2][r], s[mf][3][r]));
        #pragma unroll
        for (int off = 1; off < 16; off <<= 1)
            #pragma unroll
            for (int mf = 0; mf < 2; mf++)
                #pragma unroll
                for (int r = 0; r < 4; r++)
                    mt[mf][r] = fmaxf(mt[mf][r], __shfl_xor(mt[mf][r], off));

        float rs[2][4];
        #pragma unroll
        for (int mf = 0; mf < 2; mf++)
            #pragma unroll
            for (int r = 0; r < 4; r++) {
                float mnew = fmaxf(mrow[mf][r], mt[mf][r]);
                float alpha = expf(mrow[mf][r] - mnew);
                mrow[mf][r] = mnew;
                float acc_rs = 0.f;
                #pragma unroll
                for (int nf = 0; nf < 4; nf++) {
                    float p = expf(s[mf][nf][r] - mnew);
                    s[mf][nf][r] = p;
                    acc_rs += p;
                }
                rs[mf][r] = acc_rs;
                lrow[mf][r] *= alpha;
                #pragma unroll
                for (int cf = 0; cf < 4; cf++)
                    o[mf][cf][r] *= alpha;
            }
        #pragma unroll
        for (int off = 1; off < 16; off <<= 1)
            #pragma unroll
            for (int mf = 0; mf < 2; mf++)
                #pragma unroll
                for (int r = 0; r < 4; r++)
                    rs[mf][r] += __shfl_xor(rs[mf][r], off);
        #pragma unroll
        for (int mf = 0; mf < 2; mf++)
            #pragma unroll
            for (int r = 0; r < 4; r++)
                lrow[mf][r] += rs[mf][r];

        // P -> LDS (bf16) for A-fragment relayout
        #pragma unroll
        for (int mf = 0; mf < 2; mf++)
            #pragma unroll
            for (int nf = 0; nf < 4; nf++)
                #pragma unroll
                for (int r = 0; r < 4; r++)
                    Ps[w][(mf * 16 + lg * 4 + r) * 72 + nf * 16 + ll] = f2b(s[mf][nf][r]);

        // PV
        bf16x8 pa[2][2], vf[4][2];
        #pragma unroll
        for (int rf = 0; rf < 2; rf++) {
            int row = rf * 16 + ll;
            #pragma unroll
            for (int ks = 0; ks < 2; ks++)
                pa[rf][ks] = *(const bf16x8*)(&Ps[w][row * 72 + lg * 8 + ks * 32]);
        }
        #pragma unroll
        for (int cf = 0; cf < 4; cf++) {
            int row = cf * 16 + ll;
            #pragma unroll
            for (int ks = 0; ks < 2; ks++) {
                int off = (lg * 16 + ks * 64) ^ ((row & 7) << 4);
                vf[cf][ks] = *(const bf16x8*)((const char*)Vs + row * 128 + off);
            }
        }
        #pragma unroll
        for (int ks = 0; ks < 2; ks++)
            #pragma unroll
            for (int rf = 0; rf < 2; rf++)
                #pragma unroll
                for (int cf = 0; cf < 4; cf++)
                    o[rf][cf] = __builtin_amdgcn_mfma_f32_16x16x32_bf16(pa[rf][ks], vf[cf][ks], o[rf][cf], 0, 0, 0);
    }

    // epilogue: normalize + store bf16 to attb (B,N,256)
    #pragma unroll
    for (int rf = 0; rf < 2; rf++)
        #pragma unroll
        for (int r = 0; r < 4; r++) {
            float inv = 1.f / lrow[rf][r];
            int row = q0 + w * 32 + rf * 16 + lg * 4 + r;
            #pragma unroll
            for (int cf = 0; cf < 4; cf++) {
                int dk = cf * 16 + ll;
                attb[((size_t)b * SEQ + row) * 256 + h * 64 + dk] = f2b(o[rf][cf][r] * inv);
            }
        }
}

// ---------------- mean pool (two stage) ----------------
__global__ void pool_partial(const float* __restrict__ x2, float* __restrict__ part) {
    int ch = blockIdx.x, b = blockIdx.y, d = threadIdx.x;
    float s = 0.f;
    for (int n = ch * 32; n < ch * 32 + 32; n++)
        s += x2[((size_t)b * SEQ + n) * DMODEL + d];
    part[((size_t)b * 32 + ch) * DMODEL + d] = s;
}
__global__ void pool_final(const float* __restrict__ part, float* __restrict__ pooled) {
    int b = blockIdx.x, d = threadIdx.x;
    float s = 0.f;
    for (int ch = 0; ch < 32; ch++) s += part[((size_t)b * 32 + ch) * DMODEL + d];
    pooled[b * DMODEL + d] = s * (1.f / 1024.f);
}

// ---------------- MLP head with eval BatchNorm ----------------
__global__ __launch_bounds__(128) void head_kernel(const float* __restrict__ pooled,
                                                   const float* __restrict__ h1_w, const float* __restrict__ h1_b,
                                                   const float* __restrict__ g, const float* __restrict__ be,
                                                   const float* __restrict__ mu, const float* __restrict__ var,
                                                   const float* __restrict__ h2_w, const float* __restrict__ h2_b,
                                                   float* __restrict__ out) {
    int b = blockIdx.x, j = threadIdx.x;
    __shared__ float pl[256];
    __shared__ float red[128];
    pl[j] = pooled[b * DMODEL + j];
    pl[j + 128] = pooled[b * DMODEL + j + 128];
    __syncthreads();
    float s = 0.f;
    for (int d = 0; d < 256; d++) s = fmaf(pl[d], h1_w[j * 256 + d], s);
    s += h1_b[j];
    s = (s - mu[j]) / sqrtf(var[j] + 1e-5f) * g[j] + be[j];
    s = fmaxf(s, 0.f);
    red[j] = s * h2_w[j];
    __syncthreads();
    for (int off = 64; off; off >>= 1) {
        if (j < off) red[j] += red[j + off];
        __syncthreads();
    }
    if (j == 0) out[b] = red[0] + h2_b[0];
}

// ---------------- launch ----------------
extern "C" void kernel_launch(void* const* d_in, const int* in_sizes, int n_in,
                              void* d_out, int out_size, void* d_ws, size_t ws_size,
                              hipStream_t stream) {
    (void)in_sizes; (void)n_in; (void)out_size; (void)ws_size;
    const int*   ids    = (const int*)d_in[0];
    const int*   amask  = (const int*)d_in[1];
    const float* emb_W  = (const float*)d_in[2];
    const float* emb_b  = (const float*)d_in[3];
    const float* wq = (const float*)d_in[4],  *bq = (const float*)d_in[5];
    const float* wk = (const float*)d_in[6],  *bk = (const float*)d_in[7];
    const float* wv = (const float*)d_in[8],  *bv = (const float*)d_in[9];
    const float* fcw = (const float*)d_in[10], *fcb = (const float*)d_in[11];
    const float* f1w = (const float*)d_in[12], *f1b = (const float*)d_in[13];
    const float* f2w = (const float*)d_in[14], *f2b_ = (const float*)d_in[15];
    const float* h1w = (const float*)d_in[16], *h1b = (const float*)d_in[17];
    const float* bng = (const float*)d_in[18], *bnb = (const float*)d_in[19];
    const float* bnm = (const float*)d_in[20], *bnv = (const float*)d_in[21];
    const float* h2w = (const float*)d_in[22], *h2b = (const float*)d_in[23];
    float* out = (float*)d_out;
    float* ws = (float*)d_ws;

    // workspace layout (float slots)
    const size_t O_EMBT = 0;                 // 7,680,000  (embT; reused as Qb/Kb/Vt after embed)
    const size_t O_PE   = 7680000;           // 262,144
    const size_t O_X0   = O_PE + 262144;     // 4,194,304
    const size_t O_X0B  = O_X0 + 4194304;    // 2,097,152 (bf16 x0; reused as attb)
    const size_t O_X1B  = O_X0B + 2097152;   // 2,097,152
    const size_t O_HB   = O_X1B + 2097152;   // 2,097,152
    const size_t O_X2   = O_HB + 2097152;    // 4,194,304
    const size_t O_WB   = O_X2 + 4194304;    // 196,608 (6 x 65536 bf16)
    const size_t O_PART = O_WB + 196608;     // 131,072
    const size_t O_POOL = O_PART + 131072;   // 4,096
    const size_t O_SPAN = O_POOL + 4096;

    float* embT = ws + O_EMBT;
    float* pe   = ws + O_PE;
    float* x0   = ws + O_X0;
    unsigned short* x0b = (unsigned short*)(ws + O_X0B);
    unsigned short* Qb  = (unsigned short*)(ws + O_EMBT);            // reuse embT
    unsigned short* Kb  = (unsigned short*)(ws + O_EMBT + 2097152);
    unsigned short* Vt  = (unsigned short*)(ws + O_EMBT + 4194304);
    unsigned short* attb = (unsigned short*)(ws + O_X0B);            // reuse x0b
    unsigned short* x1b = (unsigned short*)(ws + O_X1B);
    unsigned short* hb  = (unsigned short*)(ws + O_HB);
    float* x2   = ws + O_X2;
    unsigned short* wb  = (unsigned short*)(ws + O_WB);
    float* part = ws + O_PART;
    float* pooled = ws + O_POOL;
    int* spans  = (int*)(ws + O_SPAN);

    dim3 tb(32, 8);
    transpose_k<<<dim3((VOCAB + 31) / 32, 8), tb, 0, stream>>>(emb_W, embT, DMODEL, VOCAB);
    pe_kernel<<<512, 256, 0, stream>>>(pe);
    span_kernel<<<BATCH, 256, 0, stream>>>(amask, spans);
    cvt_w<<<256, 256, 0, stream>>>(wq,  wb + 0 * 65536);
    cvt_w<<<256, 256, 0, stream>>>(wk,  wb + 1 * 65536);
    cvt_w<<<256, 256, 0, stream>>>(wv,  wb + 2 * 65536);
    cvt_w<<<256, 256, 0, stream>>>(fcw, wb + 3 * 65536);
    cvt_w<<<256, 256, 0, stream>>>(f1w, wb + 4 * 65536);
    cvt_w<<<256, 256, 0, stream>>>(f2w, wb + 5 * 65536);
    embed_kernel<<<MROWS, 256, 0, stream>>>(ids, embT, emb_b, pe, x0, x0b);

    dim3 gg(2, 128);
    bgemm<1><<<gg, 256, 0, stream>>>(x0b, wb + 0 * 65536, bq, nullptr, Qb);
    bgemm<1><<<gg, 256, 0, stream>>>(x0b, wb + 1 * 65536, bk, nullptr, Kb);
    bgemm<4><<<gg, 256, 0, stream>>>(x0b, wb + 2 * 65536, bv, nullptr, Vt);

    attn_mfma<<<dim3(SEQ / 128, NHEAD, BATCH), 256, 0, stream>>>(Qb, Kb, Vt, spans, attb);

    bgemm<2><<<gg, 256, 0, stream>>>(attb, wb + 3 * 65536, fcb, x0, x1b);
    bgemm<3><<<gg, 256, 0, stream>>>(x1b,  wb + 4 * 65536, f1b, nullptr, hb);
    bgemm<0><<<gg, 256, 0, stream>>>(hb,   wb + 5 * 65536, f2b_, nullptr, x2);

    pool_partial<<<dim3(32, BATCH), 256, 0, stream>>>(x2, part);
    pool_final<<<BATCH, 256, 0, stream>>>(part, pooled);
    head_kernel<<<BATCH, 128, 0, stream>>>(pooled, h1w, h1b, bng, bnb, bnm, bnv, h2w, h2b, out);
}

// Round 3
// 193.816 us; speedup vs baseline: 2.8073x; 1.0188x over previous
//
#include <hip/hip_runtime.h>
#include <math.h>

#define VOCAB 30000
#define DMODEL 256
#define NHEAD 4
#define SEQ 1024
#define BATCH 16
#define MROWS (BATCH*SEQ)   // 16384
#define SL2 0.18033688011112042f            // 0.125 * log2(e)
#define NEG2 (-1.4426950408889634e10f)      // -1e10 * log2(e)
#define THR2 12.0f

typedef __attribute__((ext_vector_type(8))) short bf16x8;
typedef __attribute__((ext_vector_type(4))) float f32x4;

#if __has_builtin(__builtin_amdgcn_exp2f)
#define EXP2F __builtin_amdgcn_exp2f
#else
#define EXP2F exp2f
#endif

__device__ __forceinline__ unsigned short f2b(float f) {
    unsigned int u = __float_as_uint(f);
    unsigned int r = (u + 0x7FFFu + ((u >> 16) & 1u)) >> 16;
    return (unsigned short)r;
}

// ---------------- transpose (R x C) -> (C x R), fp32 (embedding table only) ----------------
__global__ void transpose_k(const float* __restrict__ in, float* __restrict__ out, int R, int C) {
    __shared__ float t[32][33];
    int c0 = blockIdx.x * 32, r0 = blockIdx.y * 32;
    int tx = threadIdx.x, ty = threadIdx.y; // 32 x 8
    for (int i = 0; i < 32; i += 8) {
        int r = r0 + ty + i, c = c0 + tx;
        if (r < R && c < C) t[ty + i][tx] = in[(size_t)r * C + c];
    }
    __syncthreads();
    for (int i = 0; i < 32; i += 8) {
        int c = c0 + ty + i, r = r0 + tx;
        if (c < C && r < R) out[(size_t)c * R + r] = t[tx][ty + i];
    }
}

// ---------------- positional encoding (f64 math, shared down[] table) ----------------
__global__ void pe2_kernel(float* __restrict__ pe) {
    __shared__ double down[128];
    int t = threadIdx.x;
    if (t < 128) down[t] = exp((double)(2 * t) * (-9.210340371976184 / 256.0));
    __syncthreads();
    int d2 = t & 127, half = t >> 7;
    #pragma unroll
    for (int i = 0; i < 8; i++) {
        int n = blockIdx.x * 16 + half * 8 + i;
        double ang = (double)n * down[d2];
        pe[n * DMODEL + 2 * d2]     = (float)(sin(ang) * 0.1);
        pe[n * DMODEL + 2 * d2 + 1] = (float)(cos(ang) * 0.1);
    }
}

// ---------------- per-batch span from attention_mask ----------------
__global__ void span_kernel(const int* __restrict__ mask, int* __restrict__ spans) {
    int b = blockIdx.x;
    __shared__ int smin, smax;
    if (threadIdx.x == 0) { smin = SEQ; smax = -1; }
    __syncthreads();
    int lmin = SEQ, lmax = -1;
    for (int i = threadIdx.x; i < SEQ; i += 256) {
        if (mask[b * SEQ + i] != 0) { lmin = min(lmin, i); lmax = max(lmax, i); }
    }
    atomicMin(&smin, lmin);
    atomicMax(&smax, lmax);
    __syncthreads();
    if (threadIdx.x == 0) {
        int st, en;
        if (smax < 0) { st = 0; en = SEQ - 1; }
        else          { st = smin; en = smax; }
        spans[b * 2] = st; spans[b * 2 + 1] = en;
    }
}

// ---------------- qkv weight+bias convert (one launch) ----------------
__global__ void cvt_qkv(const float* __restrict__ wq, const float* __restrict__ wk,
                        const float* __restrict__ wv, const float* __restrict__ bq,
                        const float* __restrict__ bk, const float* __restrict__ bv,
                        unsigned short* __restrict__ wqkv, float* __restrict__ bias768) {
    int blk = blockIdx.x;
    if (blk < 768) {
        const float* src = (blk < 256) ? wq : (blk < 512) ? wk : wv;
        wqkv[blk * 256 + threadIdx.x] = f2b(src[(blk & 255) * 256 + threadIdx.x]);
    } else {
        for (int j = threadIdx.x; j < 768; j += 256)
            bias768[j] = (j < 256) ? bq[j] : (j < 512) ? bk[j - 256] : bv[j - 512];
    }
}

// ---------------- fc/ff1/ff2 weight convert (one launch) ----------------
__global__ void cvt3(const float* __restrict__ w0, const float* __restrict__ w1,
                     const float* __restrict__ w2, unsigned short* __restrict__ wb) {
    int blk = blockIdx.x;
    const float* src = (blk < 256) ? w0 : (blk < 512) ? w1 : w2;
    wb[blk * 256 + threadIdx.x] = f2b(src[(blk & 255) * 256 + threadIdx.x]);
}

// ---------------- embedding gather + pos enc -> x0 (fp32) + x0b (bf16) ----------------
__global__ void embed_kernel(const int* __restrict__ ids, const float* __restrict__ embT,
                             const float* __restrict__ emb_b, const float* __restrict__ pe,
                             float* __restrict__ x0, unsigned short* __restrict__ x0b) {
    int bn = blockIdx.x;
    int d = threadIdx.x;
    int id = ids[bn];
    int n = bn & (SEQ - 1);
    float v = embT[(size_t)id * DMODEL + d] + emb_b[d] + pe[n * DMODEL + d];
    x0[(size_t)bn * DMODEL + d] = v;
    x0b[(size_t)bn * DMODEL + d] = f2b(v);
}

// ---------------- bf16 MFMA GEMM: C = A(16384xK) @ W^T ----------------
// MODE 0: fp32 out (+bias)          MODE 2: bf16 out (+bias+residual fp32)
// MODE 3: bf16 out (+bias+gelu)     MODE 5: fused QKV scatter (Q scaled by SL2; V transposed)
template <int MODE>
__global__ __launch_bounds__(256) void bgemm(const unsigned short* __restrict__ A,
                                             const unsigned short* __restrict__ W,
                                             const float* __restrict__ bias,
                                             const float* __restrict__ Rres,
                                             void* __restrict__ Cout,
                                             void* __restrict__ Cout2,
                                             void* __restrict__ Cout3) {
    __shared__ unsigned short As[128 * 64];
    __shared__ unsigned short Bs[128 * 64];
    int tid = threadIdx.x;
    int n0 = blockIdx.x * 128, m0 = blockIdx.y * 128;
    int w = tid >> 6, l = tid & 63;
    int wr = (w >> 1) * 64, wc = (w & 1) * 64;
    int lg = l >> 4, ll = l & 15;
    f32x4 acc[4][4] = {};

    for (int k0 = 0; k0 < 256; k0 += 64) {
        __syncthreads();
        #pragma unroll
        for (int i = 0; i < 4; i++) {
            int s = tid + i * 256;            // 0..1023
            int row = s >> 3;                 // 0..127
            int kb = (s & 7) * 16;            // byte offset in 128B row chunk
            int swz = kb ^ ((row & 7) << 4);
            float4 av = *(const float4*)((const char*)A + (size_t)(m0 + row) * 512 + k0 * 2 + kb);
            *(float4*)((char*)As + row * 128 + swz) = av;
            float4 bv = *(const float4*)((const char*)W + (size_t)(n0 + row) * 512 + k0 * 2 + kb);
            *(float4*)((char*)Bs + row * 128 + swz) = bv;
        }
        __syncthreads();

        bf16x8 af[4][2], bf[4][2];
        #pragma unroll
        for (int mf = 0; mf < 4; mf++) {
            int row = wr + mf * 16 + ll;
            #pragma unroll
            for (int ks = 0; ks < 2; ks++) {
                int off = ((lg * 16 + ks * 64)) ^ ((row & 7) << 4);
                af[mf][ks] = *(const bf16x8*)((const char*)As + row * 128 + off);
            }
        }
        #pragma unroll
        for (int nf = 0; nf < 4; nf++) {
            int row = wc + nf * 16 + ll;
            #pragma unroll
            for (int ks = 0; ks < 2; ks++) {
                int off = ((lg * 16 + ks * 64)) ^ ((row & 7) << 4);
                bf[nf][ks] = *(const bf16x8*)((const char*)Bs + row * 128 + off);
            }
        }
        #pragma unroll
        for (int ks = 0; ks < 2; ks++)
            #pragma unroll
            for (int mf = 0; mf < 4; mf++)
                #pragma unroll
                for (int nf = 0; nf < 4; nf++)
                    acc[mf][nf] = __builtin_amdgcn_mfma_f32_16x16x32_bf16(af[mf][ks], bf[nf][ks], acc[mf][nf], 0, 0, 0);
    }

    float bcol[4];
    #pragma unroll
    for (int nf = 0; nf < 4; nf++) bcol[nf] = bias[n0 + wc + nf * 16 + ll];

    #pragma unroll
    for (int mf = 0; mf < 4; mf++) {
        #pragma unroll
        for (int r = 0; r < 4; r++) {
            int m = m0 + wr + mf * 16 + lg * 4 + r;
            #pragma unroll
            for (int nf = 0; nf < 4; nf++) {
                int n = n0 + wc + nf * 16 + ll;
                float v = acc[mf][nf][r] + bcol[nf];
                if (MODE == 2) v += Rres[(size_t)m * 256 + n];
                if (MODE == 3) v = 0.5f * v * (1.f + erff(v * 0.70710678118654752f));
                if (MODE == 0) {
                    ((float*)Cout)[(size_t)m * 256 + n] = v;
                } else if (MODE == 5) {
                    int which = n >> 8, e = n & 255, hh = e >> 6, dk = e & 63;
                    int bb = m >> 10, ns = m & 1023;
                    if (which == 0)
                        ((unsigned short*)Cout)[((((size_t)bb * 4 + hh) * 1024) + ns) * 64 + dk] = f2b(v * SL2);
                    else if (which == 1)
                        ((unsigned short*)Cout2)[((((size_t)bb * 4 + hh) * 1024) + ns) * 64 + dk] = f2b(v);
                    else
                        ((unsigned short*)Cout3)[((((size_t)bb * 4 + hh) * 64) + dk) * 1024 + ns] = f2b(v);
                } else {
                    ((unsigned short*)Cout)[(size_t)m * 256 + n] = f2b(v);
                }
            }
        }
    }
}

// ---------------- bf16 MFMA flash attention, 1 wave / 32 q-rows, no barriers ----------------
// Q (pre-scaled by SL2), K: (B,H,N,64) bf16; Vt: (B,H,64,N) bf16; out attb: (B,N,256) bf16
__global__ __launch_bounds__(64) void attn_mfma(const unsigned short* __restrict__ Qb,
                                                const unsigned short* __restrict__ Kb,
                                                const unsigned short* __restrict__ Vt,
                                                const int* __restrict__ spans,
                                                unsigned short* __restrict__ attb) {
    __shared__ __align__(16) unsigned short Ps[32 * 72];
    int b = blockIdx.z, h = blockIdx.y;
    int q0 = blockIdx.x * 32;
    int l = threadIdx.x;
    int lg = l >> 4, ll = l & 15;
    const size_t bh = (size_t)(b * 4 + h);
    const char* Kp = (const char*)(Kb + bh * SEQ * 64);
    const char* Vp = (const char*)(Vt + bh * (size_t)64 * SEQ);
    const unsigned short* Qp = Qb + bh * SEQ * 64;
    int start = spans[b * 2], end = spans[b * 2 + 1];

    bf16x8 qf[2][2];
    #pragma unroll
    for (int mf = 0; mf < 2; mf++)
        #pragma unroll
        for (int ks = 0; ks < 2; ks++)
            qf[mf][ks] = *(const bf16x8*)(Qp + (size_t)(q0 + mf * 16 + ll) * 64 + lg * 8 + ks * 32);

    f32x4 o[2][4] = {};
    float mrow[2][4], lrow[2][4];
    bool rowok[2][4];
    #pragma unroll
    for (int mf = 0; mf < 2; mf++)
        #pragma unroll
        for (int r = 0; r < 4; r++) {
            mrow[mf][r] = -INFINITY; lrow[mf][r] = 0.f;
            int rr = q0 + mf * 16 + lg * 4 + r;
            rowok[mf][r] = (rr >= start) && (rr < end);
        }

    const char* kbase = Kp + (size_t)ll * 128 + lg * 16;
    const char* vbase = Vp + (size_t)ll * 2048 + lg * 16;

    for (int ct = 0; ct < 16; ct++) {
        int kv0 = ct * 64;

        // K fragments straight from global (L2-resident)
        bf16x8 kf[4][2];
        #pragma unroll
        for (int nf = 0; nf < 4; nf++)
            #pragma unroll
            for (int ks = 0; ks < 2; ks++)
                kf[nf][ks] = *(const bf16x8*)(kbase + (size_t)kv0 * 128 + nf * 2048 + ks * 64);

        f32x4 s[2][4] = {};
        #pragma unroll
        for (int ks = 0; ks < 2; ks++)
            #pragma unroll
            for (int mf = 0; mf < 2; mf++)
                #pragma unroll
                for (int nf = 0; nf < 4; nf++)
                    s[mf][nf] = __builtin_amdgcn_mfma_f32_16x16x32_bf16(qf[mf][ks], kf[nf][ks], s[mf][nf], 0, 0, 0);

        // mask (scores already log2-scaled; fp32 swamping matches ref exactly)
        bool colok[4];
        #pragma unroll
        for (int nf = 0; nf < 4; nf++) {
            int c = kv0 + nf * 16 + ll;
            colok[nf] = (c >= start) && (c < end);
        }
        #pragma unroll
        for (int mf = 0; mf < 2; mf++)
            #pragma unroll
            for (int nf = 0; nf < 4; nf++)
                #pragma unroll
                for (int r = 0; r < 4; r++)
                    if (!(rowok[mf][r] && colok[nf])) s[mf][nf][r] += NEG2;

        // row max (16-lane groups own rows)
        float mt[2][4];
        #pragma unroll
        for (int mf = 0; mf < 2; mf++)
            #pragma unroll
            for (int r = 0; r < 4; r++)
                mt[mf][r] = fmaxf(fmaxf(s[mf][0][r], s[mf][1][r]), fmaxf(s[mf][2][r], s[mf][3][r]));
        #pragma unroll
        for (int off = 1; off < 16; off <<= 1)
            #pragma unroll
            for (int mf = 0; mf < 2; mf++)
                #pragma unroll
                for (int r = 0; r < 4; r++)
                    mt[mf][r] = fmaxf(mt[mf][r], __shfl_xor(mt[mf][r], off));

        // defer-max: only rescale when max grew past threshold
        bool ex = false;
        #pragma unroll
        for (int mf = 0; mf < 2; mf++)
            #pragma unroll
            for (int r = 0; r < 4; r++)
                ex = ex || (mt[mf][r] > mrow[mf][r] + THR2);
        if (__any(ex)) {
            #pragma unroll
            for (int mf = 0; mf < 2; mf++)
                #pragma unroll
                for (int r = 0; r < 4; r++) {
                    float mnew = fmaxf(mrow[mf][r], mt[mf][r]);
                    float alpha = EXP2F(mrow[mf][r] - mnew);
                    mrow[mf][r] = mnew;
                    lrow[mf][r] *= alpha;
                    #pragma unroll
                    for (int cf = 0; cf < 4; cf++)
                        o[mf][cf][r] *= alpha;
                }
        }

        // p = exp2(s - m), row sums
        float rs[2][4];
        #pragma unroll
        for (int mf = 0; mf < 2; mf++)
            #pragma unroll
            for (int r = 0; r < 4; r++) {
                float acc_rs = 0.f;
                #pragma unroll
                for (int nf = 0; nf < 4; nf++) {
                    float p = EXP2F(s[mf][nf][r] - mrow[mf][r]);
                    s[mf][nf][r] = p;
                    acc_rs += p;
                }
                rs[mf][r] = acc_rs;
            }
        #pragma unroll
        for (int off = 1; off < 16; off <<= 1)
            #pragma unroll
            for (int mf = 0; mf < 2; mf++)
                #pragma unroll
                for (int r = 0; r < 4; r++)
                    rs[mf][r] += __shfl_xor(rs[mf][r], off);
        #pragma unroll
        for (int mf = 0; mf < 2; mf++)
            #pragma unroll
            for (int r = 0; r < 4; r++)
                lrow[mf][r] += rs[mf][r];

        // P -> per-wave LDS (bf16) for A-fragment relayout (no barrier needed)
        #pragma unroll
        for (int mf = 0; mf < 2; mf++)
            #pragma unroll
            for (int nf = 0; nf < 4; nf++)
                #pragma unroll
                for (int r = 0; r < 4; r++)
                    Ps[(mf * 16 + lg * 4 + r) * 72 + nf * 16 + ll] = f2b(s[mf][nf][r]);

        // PV: V fragments straight from global (Vt contiguous in kv)
        bf16x8 pa[2][2], vf[4][2];
        #pragma unroll
        for (int rf = 0; rf < 2; rf++) {
            int row = rf * 16 + ll;
            #pragma unroll
            for (int ks = 0; ks < 2; ks++)
                pa[rf][ks] = *(const bf16x8*)(&Ps[row * 72 + lg * 8 + ks * 32]);
        }
        #pragma unroll
        for (int cf = 0; cf < 4; cf++)
            #pragma unroll
            for (int ks = 0; ks < 2; ks++)
                vf[cf][ks] = *(const bf16x8*)(vbase + (size_t)cf * 32768 + kv0 * 2 + ks * 64);
        #pragma unroll
        for (int ks = 0; ks < 2; ks++)
            #pragma unroll
            for (int rf = 0; rf < 2; rf++)
                #pragma unroll
                for (int cf = 0; cf < 4; cf++)
                    o[rf][cf] = __builtin_amdgcn_mfma_f32_16x16x32_bf16(pa[rf][ks], vf[cf][ks], o[rf][cf], 0, 0, 0);
    }

    // epilogue: normalize + store bf16 to attb (B,N,256)
    #pragma unroll
    for (int rf = 0; rf < 2; rf++)
        #pragma unroll
        for (int r = 0; r < 4; r++) {
            float inv = 1.f / lrow[rf][r];
            int row = q0 + rf * 16 + lg * 4 + r;
            #pragma unroll
            for (int cf = 0; cf < 4; cf++) {
                int dk = cf * 16 + ll;
                attb[((size_t)b * SEQ + row) * 256 + h * 64 + dk] = f2b(o[rf][cf][r] * inv);
            }
        }
}

// ---------------- mean pool stage 1 ----------------
__global__ void pool_partial(const float* __restrict__ x2, float* __restrict__ part) {
    int ch = blockIdx.x, b = blockIdx.y, d = threadIdx.x;
    float s = 0.f;
    for (int n = ch * 32; n < ch * 32 + 32; n++)
        s += x2[((size_t)b * SEQ + n) * DMODEL + d];
    part[((size_t)b * 32 + ch) * DMODEL + d] = s;
}

// ---------------- fused pool stage 2 + MLP head (eval BatchNorm) ----------------
__global__ __launch_bounds__(128) void head2_kernel(const float* __restrict__ part,
                                                    const float* __restrict__ h1_w, const float* __restrict__ h1_b,
                                                    const float* __restrict__ g, const float* __restrict__ be,
                                                    const float* __restrict__ mu, const float* __restrict__ var,
                                                    const float* __restrict__ h2_w, const float* __restrict__ h2_b,
                                                    float* __restrict__ out) {
    int b = blockIdx.x, j = threadIdx.x;
    __shared__ float pl[256];
    __shared__ float red[128];
    float s0 = 0.f, s1 = 0.f;
    for (int ch = 0; ch < 32; ch++) {
        s0 += part[((size_t)b * 32 + ch) * DMODEL + j];
        s1 += part[((size_t)b * 32 + ch) * DMODEL + j + 128];
    }
    pl[j] = s0 * (1.f / 1024.f);
    pl[j + 128] = s1 * (1.f / 1024.f);
    __syncthreads();
    float s = 0.f;
    for (int d = 0; d < 256; d++) s = fmaf(pl[d], h1_w[j * 256 + d], s);
    s += h1_b[j];
    s = (s - mu[j]) / sqrtf(var[j] + 1e-5f) * g[j] + be[j];
    s = fmaxf(s, 0.f);
    red[j] = s * h2_w[j];
    __syncthreads();
    for (int off = 64; off; off >>= 1) {
        if (j < off) red[j] += red[j + off];
        __syncthreads();
    }
    if (j == 0) out[b] = red[0] + h2_b[0];
}

// ---------------- launch ----------------
extern "C" void kernel_launch(void* const* d_in, const int* in_sizes, int n_in,
                              void* d_out, int out_size, void* d_ws, size_t ws_size,
                              hipStream_t stream) {
    (void)in_sizes; (void)n_in; (void)out_size; (void)ws_size;
    const int*   ids    = (const int*)d_in[0];
    const int*   amask  = (const int*)d_in[1];
    const float* emb_W  = (const float*)d_in[2];
    const float* emb_b  = (const float*)d_in[3];
    const float* wq = (const float*)d_in[4],  *bq = (const float*)d_in[5];
    const float* wk = (const float*)d_in[6],  *bk = (const float*)d_in[7];
    const float* wv = (const float*)d_in[8],  *bv = (const float*)d_in[9];
    const float* fcw = (const float*)d_in[10], *fcb = (const float*)d_in[11];
    const float* f1w = (const float*)d_in[12], *f1b = (const float*)d_in[13];
    const float* f2w = (const float*)d_in[14], *f2b_ = (const float*)d_in[15];
    const float* h1w = (const float*)d_in[16], *h1b = (const float*)d_in[17];
    const float* bng = (const float*)d_in[18], *bnb = (const float*)d_in[19];
    const float* bnm = (const float*)d_in[20], *bnv = (const float*)d_in[21];
    const float* h2w = (const float*)d_in[22], *h2b = (const float*)d_in[23];
    float* out = (float*)d_out;
    float* ws = (float*)d_ws;

    // workspace layout (float units)
    const size_t O_EMBT = 0;                       // 7,680,000 (embT; reused as Qb/Kb/Vt)
    const size_t O_PE   = 7680000;                 // 262,144
    const size_t O_X0   = O_PE + 262144;           // 4,194,304
    const size_t O_X0B  = O_X0 + 4194304;          // 2,097,152 (bf16 x0; reused as attb)
    const size_t O_X1B  = O_X0B + 2097152;         // 2,097,152
    const size_t O_HB   = O_X1B + 2097152;         // 2,097,152
    const size_t O_X2   = O_HB + 2097152;          // 4,194,304
    const size_t O_WB   = O_X2 + 4194304;          // 196,608 (wqkv 3x64K + wb3 3x64K shorts)
    const size_t O_B768 = O_WB + 196608;           // 768
    const size_t O_PART = O_B768 + 768;            // 131,072
    const size_t O_POOL = O_PART + 131072;         // 4,096
    const size_t O_SPAN = O_POOL + 4096;

    float* embT = ws + O_EMBT;
    float* pe   = ws + O_PE;
    float* x0   = ws + O_X0;
    unsigned short* x0b = (unsigned short*)(ws + O_X0B);
    unsigned short* Qb  = (unsigned short*)(ws + O_EMBT);            // reuse embT
    unsigned short* Kb  = (unsigned short*)(ws + O_EMBT + 2097152);
    unsigned short* Vt  = (unsigned short*)(ws + O_EMBT + 4194304);
    unsigned short* attb = (unsigned short*)(ws + O_X0B);            // reuse x0b
    unsigned short* x1b = (unsigned short*)(ws + O_X1B);
    unsigned short* hb  = (unsigned short*)(ws + O_HB);
    float* x2   = ws + O_X2;
    unsigned short* wqkv = (unsigned short*)(ws + O_WB);             // 768x256 bf16
    unsigned short* wb3  = wqkv + 3 * 65536;                         // fc/f1/f2
    float* bias768 = ws + O_B768;
    float* part = ws + O_PART;
    float* pooled_unused = ws + O_POOL; (void)pooled_unused;
    int* spans  = (int*)(ws + O_SPAN);

    dim3 tb(32, 8);
    transpose_k<<<dim3((VOCAB + 31) / 32, 8), tb, 0, stream>>>(emb_W, embT, DMODEL, VOCAB);
    pe2_kernel<<<64, 256, 0, stream>>>(pe);
    span_kernel<<<BATCH, 256, 0, stream>>>(amask, spans);
    cvt_qkv<<<769, 256, 0, stream>>>(wq, wk, wv, bq, bk, bv, wqkv, bias768);
    cvt3<<<768, 256, 0, stream>>>(fcw, f1w, f2w, wb3);
    embed_kernel<<<MROWS, 256, 0, stream>>>(ids, embT, emb_b, pe, x0, x0b);

    // fused QKV: N=768
    bgemm<5><<<dim3(6, 128), 256, 0, stream>>>(x0b, wqkv, bias768, nullptr, Qb, Kb, Vt);

    attn_mfma<<<dim3(SEQ / 32, NHEAD, BATCH), 64, 0, stream>>>(Qb, Kb, Vt, spans, attb);

    dim3 gg(2, 128);
    bgemm<2><<<gg, 256, 0, stream>>>(attb, wb3 + 0 * 65536, fcb, x0, x1b, nullptr, nullptr);
    bgemm<3><<<gg, 256, 0, stream>>>(x1b,  wb3 + 1 * 65536, f1b, nullptr, hb, nullptr, nullptr);
    bgemm<0><<<gg, 256, 0, stream>>>(hb,   wb3 + 2 * 65536, f2b_, nullptr, x2, nullptr, nullptr);

    pool_partial<<<dim3(32, BATCH), 256, 0, stream>>>(x2, part);
    head2_kernel<<<BATCH, 128, 0, stream>>>(part, h1w, h1b, bng, bnb, bnm, bnv, h2w, h2b, out);
}